// Round 1
// baseline (285.401 us; speedup 1.0000x reference)
//
#include <hip/hip_runtime.h>

// TinyAttention on MI355X: b=4, t=2048, d=1024, single head.
// R8: port QKV + proj GEMMs to the 256x256 8-phase counted-vmcnt structure
// (T2 swizzle + T3/T4 phase pipeline + T5 setprio), 16x16x32 bf16 MFMA,
// K-split LDS halves, global_load_lds(16B) with pre-swizzled source.
// S (exp+rowsum) and PV stay on the verified 128x128 2-barrier kernel.

typedef __bf16 bf16x8_t __attribute__((ext_vector_type(8)));
typedef float  f32x4_t  __attribute__((ext_vector_type(4)));
typedef float  f32x16_t __attribute__((ext_vector_type(16)));
typedef unsigned short u16;

struct alignas(8) u16x4 { u16 x, y, z, w; };

__device__ inline float bf2f(u16 u) {
  union { unsigned u; float f; } c; c.u = ((unsigned)u) << 16; return c.f;
}
__device__ inline u16 f2bf(float f) {  // round-to-nearest-even
  union { float f; unsigned u; } c; c.f = f;
  unsigned r = c.u + 0x7fffu + ((c.u >> 16) & 1u);
  return (u16)(r >> 16);
}

// ===========================================================================
// 256x256 8-phase GEMM (A row-major [M][K], B^T row-major [N][K], bf16 in)
// OUTMODE: 1 = f32 row-major + bias (proj), 2 = QKV split (qk | vT col-major)
// Geometry: BM=BN=256, BK=64 (2 k-halves of 32), 8 waves (2M x 4N),
// wave tile 128x64 = 8 m-frags x 4 n-frags of 16x16. LDS 128 KiB:
// per operand 2 bufs x [2 ksh][256 rows][32 k] bf16 (rows = 64 B).
// Swizzle (both sides): chunk16 c ^= (row>>1)&3  -> conflict-free ds_read_b128.
// Pipeline: stage order per K-tile t: B(t,0)@p1, A(t,1)@p2, B(t,1)@p3,
// A(t+2... shifted so every half-tile is vmcnt(6)-confirmed 3 halves early.
// ===========================================================================

#define BAR __builtin_amdgcn_s_barrier()
#define SCB __builtin_amdgcn_sched_barrier(0)
#define LGK asm volatile("s_waitcnt lgkmcnt(0)" ::: "memory")

#define STG(pst, base_, ld2, t_, ksh_)                                         \
  { const char* s0_ = (pst) + ((t_) * 64 + (ksh_) * 32) * 2;                   \
    char* d0_ = (base_) + (((t_) & 1) << 15) + ((ksh_) << 14) + ldst;          \
    __builtin_amdgcn_global_load_lds(                                          \
        (const __attribute__((address_space(1))) unsigned int*)s0_,            \
        (__attribute__((address_space(3))) unsigned int*)d0_, 16, 0, 0);       \
    __builtin_amdgcn_global_load_lds(                                          \
        (const __attribute__((address_space(1))) unsigned int*)(s0_ + 128 * (ld2)), \
        (__attribute__((address_space(3))) unsigned int*)(d0_ + 8192), 16, 0, 0); }

#define RD_A(lAb, ks, mh)                                                      \
  a0 = *(const bf16x8_t*)((lAb) + (ks) * 16384 + (mh) * 4096 + 0 * 1024);      \
  a1 = *(const bf16x8_t*)((lAb) + (ks) * 16384 + (mh) * 4096 + 1 * 1024);      \
  a2 = *(const bf16x8_t*)((lAb) + (ks) * 16384 + (mh) * 4096 + 2 * 1024);      \
  a3 = *(const bf16x8_t*)((lAb) + (ks) * 16384 + (mh) * 4096 + 3 * 1024);

#define RD_B(lBb, ks)                                                          \
  b0 = *(const bf16x8_t*)((lBb) + (ks) * 16384 + 0 * 1024);                    \
  b1 = *(const bf16x8_t*)((lBb) + (ks) * 16384 + 1 * 1024);                    \
  b2 = *(const bf16x8_t*)((lBb) + (ks) * 16384 + 2 * 1024);                    \
  b3 = *(const bf16x8_t*)((lBb) + (ks) * 16384 + 3 * 1024);

#define MM(mh)                                                                 \
  acc[(mh)*4+0][0] = __builtin_amdgcn_mfma_f32_16x16x32_bf16(a0, b0, acc[(mh)*4+0][0], 0, 0, 0); \
  acc[(mh)*4+0][1] = __builtin_amdgcn_mfma_f32_16x16x32_bf16(a0, b1, acc[(mh)*4+0][1], 0, 0, 0); \
  acc[(mh)*4+0][2] = __builtin_amdgcn_mfma_f32_16x16x32_bf16(a0, b2, acc[(mh)*4+0][2], 0, 0, 0); \
  acc[(mh)*4+0][3] = __builtin_amdgcn_mfma_f32_16x16x32_bf16(a0, b3, acc[(mh)*4+0][3], 0, 0, 0); \
  acc[(mh)*4+1][0] = __builtin_amdgcn_mfma_f32_16x16x32_bf16(a1, b0, acc[(mh)*4+1][0], 0, 0, 0); \
  acc[(mh)*4+1][1] = __builtin_amdgcn_mfma_f32_16x16x32_bf16(a1, b1, acc[(mh)*4+1][1], 0, 0, 0); \
  acc[(mh)*4+1][2] = __builtin_amdgcn_mfma_f32_16x16x32_bf16(a1, b2, acc[(mh)*4+1][2], 0, 0, 0); \
  acc[(mh)*4+1][3] = __builtin_amdgcn_mfma_f32_16x16x32_bf16(a1, b3, acc[(mh)*4+1][3], 0, 0, 0); \
  acc[(mh)*4+2][0] = __builtin_amdgcn_mfma_f32_16x16x32_bf16(a2, b0, acc[(mh)*4+2][0], 0, 0, 0); \
  acc[(mh)*4+2][1] = __builtin_amdgcn_mfma_f32_16x16x32_bf16(a2, b1, acc[(mh)*4+2][1], 0, 0, 0); \
  acc[(mh)*4+2][2] = __builtin_amdgcn_mfma_f32_16x16x32_bf16(a2, b2, acc[(mh)*4+2][2], 0, 0, 0); \
  acc[(mh)*4+2][3] = __builtin_amdgcn_mfma_f32_16x16x32_bf16(a2, b3, acc[(mh)*4+2][3], 0, 0, 0); \
  acc[(mh)*4+3][0] = __builtin_amdgcn_mfma_f32_16x16x32_bf16(a3, b0, acc[(mh)*4+3][0], 0, 0, 0); \
  acc[(mh)*4+3][1] = __builtin_amdgcn_mfma_f32_16x16x32_bf16(a3, b1, acc[(mh)*4+3][1], 0, 0, 0); \
  acc[(mh)*4+3][2] = __builtin_amdgcn_mfma_f32_16x16x32_bf16(a3, b2, acc[(mh)*4+3][2], 0, 0, 0); \
  acc[(mh)*4+3][3] = __builtin_amdgcn_mfma_f32_16x16x32_bf16(a3, b3, acc[(mh)*4+3][3], 0, 0, 0);

template<int OUTMODE>
__global__ __launch_bounds__(512, 2)
void gemm8p(const u16* __restrict__ A, const u16* __restrict__ B,
            void* __restrict__ Cv, u16* __restrict__ C2,
            const float* __restrict__ bias,
            int K, int lda, int ldb, int ldc)
{
  // XCD-aware bijective swizzle (grid count divisible by 8 for our launches)
  const int nx  = gridDim.x;
  const int nwg = nx * gridDim.y;
  const int lin = blockIdx.y * nx + blockIdx.x;
  const int cpx = nwg >> 3;
  const int swz = (lin & 7) * cpx + (lin >> 3);
  const int bn0 = (swz % nx) * 256;
  const int bm0 = (swz / nx) * 256;

  __shared__ __align__(16) u16 lds[65536];   // A: 64 KiB | B: 64 KiB
  char* const baseA = (char*)lds;
  char* const baseB = (char*)lds + 65536;

  const int tid  = threadIdx.x;
  const int lane = tid & 63;
  const int wv   = tid >> 6;
  const int wrow = ((wv >> 2) & 1) * 128;   // wave: 2M x 4N, tile 128x64
  const int wcol = (wv & 3) * 64;
  const int l15  = lane & 15;
  // per-lane swizzled read offset: row l15 (64B rows), chunk (l>>4)^((row>>1)&3)
  const int rd_pl = l15 * 64 + ((((lane >> 4) ^ (l15 >> 1)) & 3) << 4);

  // staging: thread t -> row t>>2 (call q adds 128), dest chunk t&3,
  // source chunk pre-swizzled: c_src = (t&3) ^ ((row>>1)&3) = (t&3)^((t>>3)&3)
  const int c_src = (tid & 3) ^ ((tid >> 3) & 3);
  const int s_row = tid >> 2;
  const int ldst  = tid * 16;
  const long ldA2 = (long)lda * 2, ldB2 = (long)ldb * 2;
  const char* pAst = (const char*)A + ((long)bm0 + s_row) * ldA2 + c_src * 16;
  const char* pBst = (const char*)B + ((long)bn0 + s_row) * ldB2 + c_src * 16;

  f32x4_t acc[8][4];
#pragma unroll
  for (int i = 0; i < 8; ++i)
#pragma unroll
    for (int j = 0; j < 4; ++j)
      acc[i][j] = (f32x4_t){0.f, 0.f, 0.f, 0.f};

  const int nt = K >> 6;   // assumed >= 2 (K = 1024 here)

  // prologue: A(0,0) B(0,0) A(0,1) B(0,1) A(1,0); keep 3 half-tiles in flight
  STG(pAst, baseA, ldA2, 0, 0);
  STG(pBst, baseB, ldB2, 0, 0);
  STG(pAst, baseA, ldA2, 0, 1);
  STG(pBst, baseB, ldB2, 0, 1);
  if (nt > 1) STG(pAst, baseA, ldA2, 1, 0);
  asm volatile("s_waitcnt vmcnt(6)" ::: "memory");
  BAR; SCB;

  bf16x8_t a0, a1, a2, a3, b0, b1, b2, b3;

  for (int t = 0; t < nt; ++t) {
    const char* lAb = baseA + ((t & 1) << 15) + wrow * 64 + rd_pl;
    const char* lBb = baseB + ((t & 1) << 15) + wcol * 64 + rd_pl;
    const bool st1 = (t + 1 < nt), st2 = (t + 2 < nt);

    // phase 1: ks=0 mh=0 --------------------------------------------------
    RD_B(lBb, 0);
    RD_A(lAb, 0, 0);
    if (st1) STG(pBst, baseB, ldB2, t + 1, 0);
    BAR; LGK; SCB;
    __builtin_amdgcn_s_setprio(1); MM(0); __builtin_amdgcn_s_setprio(0);
    BAR; SCB;

    // phase 2: ks=0 mh=1 --------------------------------------------------
    RD_A(lAb, 0, 1);
    if (st1) STG(pAst, baseA, ldA2, t + 1, 1);
    BAR; LGK; SCB;
    __builtin_amdgcn_s_setprio(1); MM(1); __builtin_amdgcn_s_setprio(0);
    if (st1) { asm volatile("s_waitcnt vmcnt(6)" ::: "memory"); }
    else     { asm volatile("s_waitcnt vmcnt(0)" ::: "memory"); }
    BAR; SCB;

    // phase 3: ks=1 mh=0 --------------------------------------------------
    RD_B(lBb, 1);
    RD_A(lAb, 1, 0);
    if (st1) STG(pBst, baseB, ldB2, t + 1, 1);
    BAR; LGK; SCB;
    __builtin_amdgcn_s_setprio(1); MM(0); __builtin_amdgcn_s_setprio(0);
    BAR; SCB;

    // phase 4: ks=1 mh=1 --------------------------------------------------
    RD_A(lAb, 1, 1);
    if (st2) STG(pAst, baseA, ldA2, t + 2, 0);
    BAR; LGK; SCB;
    __builtin_amdgcn_s_setprio(1); MM(1); __builtin_amdgcn_s_setprio(0);
    if (st1) {
      if (st2) { asm volatile("s_waitcnt vmcnt(6)" ::: "memory"); }
      else     { asm volatile("s_waitcnt vmcnt(4)" ::: "memory"); }
    }
    BAR; SCB;
  }

  // epilogue: 16x16 D layout col=lane&15, row=(lane>>4)*4+reg
  const int rb = bm0 + wrow + ((lane >> 4) << 2);

  if (OUTMODE == 2) {
    if (bn0 >= 2048) {
      // V columns: vT[batch][dcol][s] col-major, u16x4 over 4 consecutive s
#pragma unroll
      for (int mi = 0; mi < 8; ++mi) {
        const int s0 = rb + mi * 16;
        const int b_ = s0 >> 11;
        const int s_ = s0 & 2047;
#pragma unroll
        for (int ni = 0; ni < 4; ++ni) {
          const int dcol = bn0 - 2048 + wcol + ni * 16 + l15;
          u16x4 o = {f2bf(acc[mi][ni][0]), f2bf(acc[mi][ni][1]),
                     f2bf(acc[mi][ni][2]), f2bf(acc[mi][ni][3])};
          *(u16x4*)&C2[(((long)b_ * 1024 + dcol) << 11) + s_] = o;
        }
      }
    } else {
      u16* Cb16 = (u16*)Cv;
#pragma unroll
      for (int mi = 0; mi < 8; ++mi)
#pragma unroll
        for (int ni = 0; ni < 4; ++ni) {
          const int col = bn0 + wcol + ni * 16 + l15;
#pragma unroll
          for (int r = 0; r < 4; ++r)
            Cb16[(long)(rb + mi * 16 + r) * ldc + col] = f2bf(acc[mi][ni][r]);
        }
    }
    return;
  }

  // OUTMODE 1: f32 + bias (proj)
  float* Cf32 = (float*)Cv;
#pragma unroll
  for (int mi = 0; mi < 8; ++mi)
#pragma unroll
    for (int ni = 0; ni < 4; ++ni) {
      const int col = bn0 + wcol + ni * 16 + l15;
      const float bb = bias[col];
#pragma unroll
      for (int r = 0; r < 4; ++r)
        Cf32[(long)(rb + mi * 16 + r) * ldc + col] = acc[mi][ni][r] + bb;
    }
}

// ===========================================================================
// Legacy 128x128 kernel — still used for S (exp/causal/rowsum) and PV.
// OUTMODE: 3 = S: E=exp(scale*acc) bf16 + causal mask + atomic rowsums,
//          4 = PV: bf16 row-major, divided by rowsum[row]
// GRIDMODE: 1 = compact lower-triangular, 2 = reversed-y + K<=bm0+128
// ===========================================================================
template<int OUTMODE, int GRIDMODE>
__global__ __launch_bounds__(256, 4)
void gemm_bt(const u16* __restrict__ A, const u16* __restrict__ B,
             void* __restrict__ Cv, u16* __restrict__ C2,
             const float* __restrict__ bias, float* __restrict__ rs,
             int K, int lda, int ldb, int ldc,
             long sA, long sB, long sC)
{
  int bn0, bm0;
  if (GRIDMODE == 1) {
    const int x = blockIdx.x;                       // 0..135
    int r = (int)((sqrtf(8.f * x + 1.f) - 1.f) * 0.5f);
    while ((r + 1) * (r + 2) / 2 <= x) ++r;
    while (r * (r + 1) / 2 > x) --r;
    bm0 = r * 128;
    bn0 = (x - r * (r + 1) / 2) * 128;
  } else if (GRIDMODE == 2) {
    bn0 = blockIdx.x * 128;
    bm0 = ((int)gridDim.y - 1 - (int)blockIdx.y) * 128;  // longest K first
  } else {
    bn0 = blockIdx.x * 128;
    bm0 = blockIdx.y * 128;
  }
  const long bz = blockIdx.z;
  const u16* Ab = A + bz * sA;
  const u16* Bb = B + bz * sB;
  const int Keff = (GRIDMODE == 2) ? min(K, bm0 + 128) : K;

  // BK=64: 128 rows x 64 u16 = 16 KB per matrix, 32 KB total
  __shared__ __align__(16) u16 lA[128 * 64];
  __shared__ __align__(16) u16 lB[128 * 64];

  const int tid  = threadIdx.x;
  const int lane = tid & 63;
  const int wv   = tid >> 6;
  const int wm   = (wv >> 1) << 6;   // wave's 64-row offset
  const int wn   = (wv & 1) << 6;    // wave's 64-col offset
  const int ml   = lane & 31;        // A-row / B-col / D-col within 32-tile
  const int kh   = lane >> 5;        // k-half 0..1
  const int swzl = ml & 7;           // 3-bit row-derived chunk16 XOR

  f32x16_t acc[2][2];
#pragma unroll
  for (int i = 0; i < 2; ++i)
#pragma unroll
    for (int j = 0; j < 2; ++j)
#pragma unroll
      for (int r = 0; r < 16; ++r)
        acc[i][j][r] = 0.f;

  // Staging: LDS chunk16 (row, c) stores global chunk (row, c ^ (row&7)).
  const long ldA2 = (long)lda * 2, ldB2 = (long)ldb * 2;
  const int rowA = tid >> 3;
  const int csw  = (tid & 7) ^ (rowA & 7);
  const char* pA = (const char*)(Ab + (long)bm0 * lda) + (long)rowA * ldA2 + (csw << 4);
  const char* pB = (const char*)(Bb + (long)bn0 * ldb) + (long)rowA * ldB2 + (csw << 4);
  const int ldsbo = tid * 16;

  for (int k0 = 0; k0 < Keff; k0 += 64) {
    const long kb = (long)k0 * 2;
#pragma unroll
    for (int r = 0; r < 4; ++r)
      __builtin_amdgcn_global_load_lds(
          (const __attribute__((address_space(1))) unsigned int*)(pA + kb + (long)(r * 32) * ldA2),
          (__attribute__((address_space(3))) unsigned int*)((char*)lA + ldsbo + r * 4096), 16, 0, 0);
#pragma unroll
    for (int r = 0; r < 4; ++r)
      __builtin_amdgcn_global_load_lds(
          (const __attribute__((address_space(1))) unsigned int*)(pB + kb + (long)(r * 32) * ldB2),
          (__attribute__((address_space(3))) unsigned int*)((char*)lB + ldsbo + r * 4096), 16, 0, 0);
    __syncthreads();

    // logical k-chunk (s*2+kh) of row r lives at LDS chunk (s*2+kh)^(r&7)
#pragma unroll
    for (int s = 0; s < 4; ++s) {
      const int ck = ((s * 2 + kh) ^ swzl) << 3;   // u16 offset in 64-elem row
      bf16x8_t A0 = *(const bf16x8_t*)&lA[(wm + ml) * 64 + ck];
      bf16x8_t A1 = *(const bf16x8_t*)&lA[(wm + 32 + ml) * 64 + ck];
      bf16x8_t B0 = *(const bf16x8_t*)&lB[(wn + ml) * 64 + ck];
      bf16x8_t B1 = *(const bf16x8_t*)&lB[(wn + 32 + ml) * 64 + ck];
      acc[0][0] = __builtin_amdgcn_mfma_f32_32x32x16_bf16(A0, B0, acc[0][0], 0, 0, 0);
      acc[0][1] = __builtin_amdgcn_mfma_f32_32x32x16_bf16(A0, B1, acc[0][1], 0, 0, 0);
      acc[1][0] = __builtin_amdgcn_mfma_f32_32x32x16_bf16(A1, B0, acc[1][0], 0, 0, 0);
      acc[1][1] = __builtin_amdgcn_mfma_f32_32x32x16_bf16(A1, B1, acc[1][1], 0, 0, 0);
    }
    __syncthreads();
  }

  // epilogue: 32x32 D layout col=lane&31, row=(reg&3)+8*(reg>>2)+4*(lane>>5)
  if (OUTMODE == 3) {
    // E = exp(acc/32), causal mask on diagonal block, bf16 store, atomic rowsums.
    const float scale = 0.03125f;
    const bool diag = (bm0 == bn0);
    u16* Cb16 = (u16*)Cv + bz * sC;
    float* rsb = rs + bz * 2048;
#pragma unroll
    for (int i = 0; i < 2; ++i) {
#pragma unroll
      for (int reg = 0; reg < 16; ++reg) {
        const int grow = bm0 + wm + i * 32 + (reg & 3) + 8 * (reg >> 2) + kh * 4;
        const int col0 = bn0 + wn + ml;
        float e0 = (diag && col0 > grow)      ? 0.f : __expf(acc[i][0][reg] * scale);
        float e1 = (diag && col0 + 32 > grow) ? 0.f : __expf(acc[i][1][reg] * scale);
        Cb16[(long)grow * ldc + col0]      = f2bf(e0);
        Cb16[(long)grow * ldc + col0 + 32] = f2bf(e1);
        float rsum = e0 + e1;
#pragma unroll
        for (int m = 1; m < 32; m <<= 1) rsum += __shfl_xor(rsum, m);
        if (ml == 0) atomicAdd(&rsb[grow], rsum);
      }
    }
    return;
  }

  if (OUTMODE == 4) {
    // stage inverse rowsums through LDS (reuse lA; loop's final barrier protects)
    float* rsl = (float*)lA;
    if (tid < 128) rsl[tid] = 1.0f / rs[bz * 2048 + bm0 + tid];
    __syncthreads();
    u16* Cb16 = (u16*)Cv + bz * sC;
#pragma unroll
    for (int i = 0; i < 2; ++i)
#pragma unroll
      for (int j = 0; j < 2; ++j)
#pragma unroll
        for (int reg = 0; reg < 16; ++reg) {
          const int rl  = wm + i * 32 + (reg & 3) + 8 * (reg >> 2) + kh * 4;
          const int col = bn0 + wn + j * 32 + ml;
          Cb16[(long)(bm0 + rl) * ldc + col] = f2bf(acc[i][j][reg] * rsl[rl]);
        }
    return;
  }
}

// ---------------------------------------------------------------------------
__global__ __launch_bounds__(256)
void cvt_f32_bf16(const float* __restrict__ in, u16* __restrict__ out) {
  const int i = blockIdx.x * 256 + threadIdx.x;
  float4 v = ((const float4*)in)[i];
  u16x4 o = {f2bf(v.x), f2bf(v.y), f2bf(v.z), f2bf(v.w)};
  ((u16x4*)out)[i] = o;
}

// both weight transposes in one dispatch
__global__ __launch_bounds__(256)
void transpose_weights(const float* __restrict__ wqkv, u16* __restrict__ wqkvT,
                       const float* __restrict__ wproj, u16* __restrict__ wprojT) {
  const bool isq = blockIdx.x < 96;
  const float* in = isq ? wqkv : wproj;
  u16* out        = isq ? wqkvT : wprojT;
  const int C     = isq ? 3072 : 1024;
  const int c0 = (isq ? blockIdx.x : (blockIdx.x - 96)) * 32;
  const int r0 = blockIdx.y * 32;
  __shared__ float t[32][33];
  const int tx = threadIdx.x & 31, ty = threadIdx.x >> 5;
#pragma unroll
  for (int i = 0; i < 32; i += 8)
    t[ty + i][tx] = in[(long)(r0 + ty + i) * C + (c0 + tx)];
  __syncthreads();
#pragma unroll
  for (int i = 0; i < 32; i += 8)
    out[(long)(c0 + ty + i) * 1024 + (r0 + tx)] = f2bf(t[tx][ty + i]);
}

// ---------------------------------------------------------------------------
extern "C" void kernel_launch(void* const* d_in, const int* in_sizes, int n_in,
                              void* d_out, int out_size, void* d_ws, size_t ws_size,
                              hipStream_t stream) {
  (void)in_sizes; (void)n_in; (void)out_size; (void)ws_size;
  const float* x      = (const float*)d_in[0];
  const float* w_qkv  = (const float*)d_in[1];
  const float* w_proj = (const float*)d_in[2];
  const float* b_proj = (const float*)d_in[3];
  float* y = (float*)d_out;
  char*  ws = (char*)d_ws;

  // workspace layout
  u16* xbf    = (u16*)(ws);                  // 16 MB  x bf16; reused for attn_out
  u16* qk     = (u16*)(ws + (16l << 20));    // 32 MB  [4][2048][2048] bf16 (q | k)
  u16* wqkvT  = (u16*)(ws + (48l << 20));    //  6 MB  [3072,1024]
  u16* wprojT = (u16*)(ws + (54l << 20));    //  2 MB  [1024,1024]
  u16* vT     = (u16*)(ws + (56l << 20));    // 16 MB  [4][1024][2048]
  u16* E      = (u16*)(ws + (72l << 20));    // 32 MB  [4][2048][2048] unnormalized exp
  float* rsum = (float*)(ws + (104l << 20)); // 32 KB  [4][2048] fp32 rowsums
  u16* attn   = xbf;                         // lifetime-disjoint reuse

  // 0) zero rowsums (ws is re-poisoned 0xAA before every launch)
  hipMemsetAsync(rsum, 0, 4 * 2048 * sizeof(float), stream);
  // 1) x -> bf16
  cvt_f32_bf16<<<8192, 256, 0, stream>>>(x, xbf);
  // 2) weights -> transposed bf16
  transpose_weights<<<dim3(128, 32), 256, 0, stream>>>(w_qkv, wqkvT, w_proj, wprojT);
  // 3) qkv = x @ w_qkv : q,k -> qk (ldc 2048), v -> vT fused transpose  [8-phase]
  gemm8p<2><<<dim3(12, 32), 512, 0, stream>>>(
      xbf, wqkvT, qk, vT, nullptr, 1024, 1024, 1024, 2048);
  // 4) E = exp(q @ k^T / 32) causal, + rowsums; compact triangular grid
  gemm_bt<3, 1><<<dim3(136, 1, 4), 256, 0, stream>>>(
      qk, qk + 1024, E, nullptr, nullptr, rsum, 1024, 2048, 2048, 2048,
      (long)2048 * 2048, (long)2048 * 2048, (long)2048 * 2048);
  // 5) attn = (E @ V) / rowsum : K_eff = bm0+128, longest blocks first
  gemm_bt<4, 2><<<dim3(8, 16, 4), 256, 0, stream>>>(
      E, vT, attn, nullptr, nullptr, rsum, 2048, 2048, 2048, 1024,
      (long)2048 * 2048, (long)1024 * 2048, (long)2048 * 1024);
  // 6) y = attn @ w_proj + b_proj : fp32 out  [8-phase]
  gemm8p<1><<<dim3(4, 32), 512, 0, stream>>>(
      attn, wprojT, y, nullptr, b_proj, 1024, 1024, 1024, 1024);
}

// Round 2
// 280.818 us; speedup vs baseline: 1.0163x; 1.0163x over previous
//
#include <hip/hip_runtime.h>

// TinyAttention on MI355X: b=4, t=2048, d=1024, single head.
// R9: gemm8p restructured to 2 super-phases per K-tile (4 barriers/tile, was 8)
// with partial lgkmcnt(4) so the mh1 cluster's ds_reads are serviced under the
// mh0 MFMA pipe shadow (the m201 template's "lgkmcnt(8) if 12 reads" trick).
// Staging + counted-vmcnt schedule identical to R8 (verified). proj reverted to
// the proven legacy 128x128 kernel (512 blocks; R8's 256^2 proj used half the CUs).
// S (exp+rowsum) and PV stay on the verified 128x128 2-barrier kernel.

typedef __bf16 bf16x8_t __attribute__((ext_vector_type(8)));
typedef float  f32x4_t  __attribute__((ext_vector_type(4)));
typedef float  f32x16_t __attribute__((ext_vector_type(16)));
typedef unsigned short u16;

struct alignas(8) u16x4 { u16 x, y, z, w; };

__device__ inline float bf2f(u16 u) {
  union { unsigned u; float f; } c; c.u = ((unsigned)u) << 16; return c.f;
}
__device__ inline u16 f2bf(float f) {  // round-to-nearest-even
  union { float f; unsigned u; } c; c.f = f;
  unsigned r = c.u + 0x7fffu + ((c.u >> 16) & 1u);
  return (u16)(r >> 16);
}

// ===========================================================================
// 256x256 super-phase GEMM (A row-major [M][K], B^T row-major [N][K], bf16 in)
// OUTMODE: 2 = QKV split (qk row-major | vT col-major)
// Geometry: BM=BN=256, BK=64 (2 k-halves of 32), 8 waves (2M x 4N),
// wave tile 128x64 = 8 m-frags x 4 n-frags of 16x16. LDS 128 KiB:
// per operand 2 bufs x [2 ksh][256 rows][32 k] bf16 (rows = 64 B).
// Swizzle (both sides): chunk16 c ^= (row>>1)&3  -> conflict-free ds_read_b128.
// Per K-tile: 2 super-phases (ksh=0,1), each {12 ds_read_b128; 2 STG(2 loads ea);
// BAR; lgkmcnt(4); 16 MFMA (mh0); lgkmcnt(0); 16 MFMA (mh1); vmcnt(N); BAR}.
// vmcnt schedule: B(t+1,0)+A(t+1,1) staged in sp1, B(t+1,1)+A(t+2,0) in sp2;
// vmcnt(6) at each sp end keeps 3 half-tile-pairs in flight (never drains).
// ===========================================================================

#define BAR __builtin_amdgcn_s_barrier()
#define SCB __builtin_amdgcn_sched_barrier(0)

#define STG(pst, base_, ld2, t_, ksh_)                                         \
  { const char* s0_ = (pst) + ((t_) * 64 + (ksh_) * 32) * 2;                   \
    char* d0_ = (base_) + (((t_) & 1) << 15) + ((ksh_) << 14) + ldst;          \
    __builtin_amdgcn_global_load_lds(                                          \
        (const __attribute__((address_space(1))) unsigned int*)s0_,            \
        (__attribute__((address_space(3))) unsigned int*)d0_, 16, 0, 0);       \
    __builtin_amdgcn_global_load_lds(                                          \
        (const __attribute__((address_space(1))) unsigned int*)(s0_ + 128 * (ld2)), \
        (__attribute__((address_space(3))) unsigned int*)(d0_ + 8192), 16, 0, 0); }

// issue order matters: b0-3, a0-3 first (8 reads), a4-7 last (covered by lgkmcnt(4))
#define RD12(lAb, lBb, ks)                                                     \
  b0 = *(const bf16x8_t*)((lBb) + (ks) * 16384 + 0 * 1024);                    \
  b1 = *(const bf16x8_t*)((lBb) + (ks) * 16384 + 1 * 1024);                    \
  b2 = *(const bf16x8_t*)((lBb) + (ks) * 16384 + 2 * 1024);                    \
  b3 = *(const bf16x8_t*)((lBb) + (ks) * 16384 + 3 * 1024);                    \
  a0 = *(const bf16x8_t*)((lAb) + (ks) * 16384 + 0 * 1024);                    \
  a1 = *(const bf16x8_t*)((lAb) + (ks) * 16384 + 1 * 1024);                    \
  a2 = *(const bf16x8_t*)((lAb) + (ks) * 16384 + 2 * 1024);                    \
  a3 = *(const bf16x8_t*)((lAb) + (ks) * 16384 + 3 * 1024);                    \
  a4 = *(const bf16x8_t*)((lAb) + (ks) * 16384 + 4096 + 0 * 1024);             \
  a5 = *(const bf16x8_t*)((lAb) + (ks) * 16384 + 4096 + 1 * 1024);             \
  a6 = *(const bf16x8_t*)((lAb) + (ks) * 16384 + 4096 + 2 * 1024);             \
  a7 = *(const bf16x8_t*)((lAb) + (ks) * 16384 + 4096 + 3 * 1024);

#define MM4(r, av)                                                             \
  acc[r][0] = __builtin_amdgcn_mfma_f32_16x16x32_bf16(av, b0, acc[r][0], 0, 0, 0); \
  acc[r][1] = __builtin_amdgcn_mfma_f32_16x16x32_bf16(av, b1, acc[r][1], 0, 0, 0); \
  acc[r][2] = __builtin_amdgcn_mfma_f32_16x16x32_bf16(av, b2, acc[r][2], 0, 0, 0); \
  acc[r][3] = __builtin_amdgcn_mfma_f32_16x16x32_bf16(av, b3, acc[r][3], 0, 0, 0);

template<int OUTMODE>
__global__ __launch_bounds__(512, 2)
void gemm8p(const u16* __restrict__ A, const u16* __restrict__ B,
            void* __restrict__ Cv, u16* __restrict__ C2,
            const float* __restrict__ bias,
            int K, int lda, int ldb, int ldc)
{
  // XCD-aware bijective swizzle (grid count divisible by 8 for our launches)
  const int nx  = gridDim.x;
  const int nwg = nx * gridDim.y;
  const int lin = blockIdx.y * nx + blockIdx.x;
  const int cpx = nwg >> 3;
  const int swz = (lin & 7) * cpx + (lin >> 3);
  const int bn0 = (swz % nx) * 256;
  const int bm0 = (swz / nx) * 256;

  __shared__ __align__(16) u16 lds[65536];   // A: 64 KiB | B: 64 KiB
  char* const baseA = (char*)lds;
  char* const baseB = (char*)lds + 65536;

  const int tid  = threadIdx.x;
  const int lane = tid & 63;
  const int wv   = tid >> 6;
  const int wrow = ((wv >> 2) & 1) * 128;   // wave: 2M x 4N, tile 128x64
  const int wcol = (wv & 3) * 64;
  const int l15  = lane & 15;
  // per-lane swizzled read offset: row l15 (64B rows), chunk (l>>4)^((row>>1)&3)
  const int rd_pl = l15 * 64 + ((((lane >> 4) ^ (l15 >> 1)) & 3) << 4);

  // staging: thread t -> row t>>2, dest chunk t&3,
  // source chunk pre-swizzled: c_src = (t&3) ^ ((row>>1)&3) = (t&3)^((t>>3)&3)
  const int c_src = (tid & 3) ^ ((tid >> 3) & 3);
  const int s_row = tid >> 2;
  const int ldst  = tid * 16;
  const long ldA2 = (long)lda * 2, ldB2 = (long)ldb * 2;
  const char* pAst = (const char*)A + ((long)bm0 + s_row) * ldA2 + c_src * 16;
  const char* pBst = (const char*)B + ((long)bn0 + s_row) * ldB2 + c_src * 16;

  f32x4_t acc[8][4];
#pragma unroll
  for (int i = 0; i < 8; ++i)
#pragma unroll
    for (int j = 0; j < 4; ++j)
      acc[i][j] = (f32x4_t){0.f, 0.f, 0.f, 0.f};

  const int nt = K >> 6;   // assumed >= 2 (K = 1024 here)

  // prologue: A(0,0) B(0,0) A(0,1) B(0,1) A(1,0); keep 3 half-tile-pairs in flight
  STG(pAst, baseA, ldA2, 0, 0);
  STG(pBst, baseB, ldB2, 0, 0);
  STG(pAst, baseA, ldA2, 0, 1);
  STG(pBst, baseB, ldB2, 0, 1);
  if (nt > 1) STG(pAst, baseA, ldA2, 1, 0);
  asm volatile("s_waitcnt vmcnt(6)" ::: "memory");
  BAR; SCB;

  bf16x8_t a0, a1, a2, a3, a4, a5, a6, a7, b0, b1, b2, b3;

  for (int t = 0; t < nt; ++t) {
    const char* lAb = baseA + ((t & 1) << 15) + wrow * 64 + rd_pl;
    const char* lBb = baseB + ((t & 1) << 15) + wcol * 64 + rd_pl;
    const bool st1 = (t + 1 < nt), st2 = (t + 2 < nt);

    // super-phase 1: ks=0 ------------------------------------------------
    RD12(lAb, lBb, 0);
    if (st1) STG(pBst, baseB, ldB2, t + 1, 0);
    if (st1) STG(pAst, baseA, ldA2, t + 1, 1);
    SCB; BAR;
    asm volatile("s_waitcnt lgkmcnt(4)" ::: "memory"); SCB;
    __builtin_amdgcn_s_setprio(1);
    MM4(0, a0); MM4(1, a1); MM4(2, a2); MM4(3, a3);
    asm volatile("s_waitcnt lgkmcnt(0)" ::: "memory"); SCB;
    MM4(4, a4); MM4(5, a5); MM4(6, a6); MM4(7, a7);
    __builtin_amdgcn_s_setprio(0);
    if (st1) { asm volatile("s_waitcnt vmcnt(6)" ::: "memory"); }
    else     { asm volatile("s_waitcnt vmcnt(0)" ::: "memory"); }
    BAR; SCB;

    // super-phase 2: ks=1 ------------------------------------------------
    RD12(lAb, lBb, 1);
    if (st1) STG(pBst, baseB, ldB2, t + 1, 1);
    if (st2) STG(pAst, baseA, ldA2, t + 2, 0);
    SCB; BAR;
    asm volatile("s_waitcnt lgkmcnt(4)" ::: "memory"); SCB;
    __builtin_amdgcn_s_setprio(1);
    MM4(0, a0); MM4(1, a1); MM4(2, a2); MM4(3, a3);
    asm volatile("s_waitcnt lgkmcnt(0)" ::: "memory"); SCB;
    MM4(4, a4); MM4(5, a5); MM4(6, a6); MM4(7, a7);
    __builtin_amdgcn_s_setprio(0);
    if (st1) {
      if (st2) { asm volatile("s_waitcnt vmcnt(6)" ::: "memory"); }
      else     { asm volatile("s_waitcnt vmcnt(4)" ::: "memory"); }
    }
    BAR; SCB;
  }

  // epilogue: 16x16 D layout col=lane&15, row=(lane>>4)*4+reg
  const int rb = bm0 + wrow + ((lane >> 4) << 2);

  if (OUTMODE == 2) {
    if (bn0 >= 2048) {
      // V columns: vT[batch][dcol][s] col-major, u16x4 over 4 consecutive s
#pragma unroll
      for (int mi = 0; mi < 8; ++mi) {
        const int s0 = rb + mi * 16;
        const int b_ = s0 >> 11;
        const int s_ = s0 & 2047;
#pragma unroll
        for (int ni = 0; ni < 4; ++ni) {
          const int dcol = bn0 - 2048 + wcol + ni * 16 + l15;
          u16x4 o = {f2bf(acc[mi][ni][0]), f2bf(acc[mi][ni][1]),
                     f2bf(acc[mi][ni][2]), f2bf(acc[mi][ni][3])};
          *(u16x4*)&C2[(((long)b_ * 1024 + dcol) << 11) + s_] = o;
        }
      }
    } else {
      u16* Cb16 = (u16*)Cv;
#pragma unroll
      for (int mi = 0; mi < 8; ++mi)
#pragma unroll
        for (int ni = 0; ni < 4; ++ni) {
          const int col = bn0 + wcol + ni * 16 + l15;
#pragma unroll
          for (int r = 0; r < 4; ++r)
            Cb16[(long)(rb + mi * 16 + r) * ldc + col] = f2bf(acc[mi][ni][r]);
        }
    }
    return;
  }

  // OUTMODE 1: f32 + bias (unused; proj runs on legacy kernel)
  float* Cf32 = (float*)Cv;
#pragma unroll
  for (int mi = 0; mi < 8; ++mi)
#pragma unroll
    for (int ni = 0; ni < 4; ++ni) {
      const int col = bn0 + wcol + ni * 16 + l15;
      const float bb = bias[col];
#pragma unroll
      for (int r = 0; r < 4; ++r)
        Cf32[(long)(rb + mi * 16 + r) * ldc + col] = acc[mi][ni][r] + bb;
    }
}

// ===========================================================================
// Legacy 128x128 kernel — used for S (exp/causal/rowsum), PV, and proj.
// OUTMODE: 1 = f32 row-major + bias (proj),
//          3 = S: E=exp(scale*acc) bf16 + causal mask + atomic rowsums,
//          4 = PV: bf16 row-major, divided by rowsum[row]
// GRIDMODE: 0 = normal, 1 = compact lower-triangular, 2 = reversed-y + K<=bm0+128
// ===========================================================================
template<int OUTMODE, int GRIDMODE>
__global__ __launch_bounds__(256, 4)
void gemm_bt(const u16* __restrict__ A, const u16* __restrict__ B,
             void* __restrict__ Cv, u16* __restrict__ C2,
             const float* __restrict__ bias, float* __restrict__ rs,
             int K, int lda, int ldb, int ldc,
             long sA, long sB, long sC)
{
  int bn0, bm0;
  if (GRIDMODE == 1) {
    const int x = blockIdx.x;                       // 0..135
    int r = (int)((sqrtf(8.f * x + 1.f) - 1.f) * 0.5f);
    while ((r + 1) * (r + 2) / 2 <= x) ++r;
    while (r * (r + 1) / 2 > x) --r;
    bm0 = r * 128;
    bn0 = (x - r * (r + 1) / 2) * 128;
  } else if (GRIDMODE == 2) {
    bn0 = blockIdx.x * 128;
    bm0 = ((int)gridDim.y - 1 - (int)blockIdx.y) * 128;  // longest K first
  } else {
    bn0 = blockIdx.x * 128;
    bm0 = blockIdx.y * 128;
  }
  const long bz = blockIdx.z;
  const u16* Ab = A + bz * sA;
  const u16* Bb = B + bz * sB;
  const int Keff = (GRIDMODE == 2) ? min(K, bm0 + 128) : K;

  // BK=64: 128 rows x 64 u16 = 16 KB per matrix, 32 KB total
  __shared__ __align__(16) u16 lA[128 * 64];
  __shared__ __align__(16) u16 lB[128 * 64];

  const int tid  = threadIdx.x;
  const int lane = tid & 63;
  const int wv   = tid >> 6;
  const int wm   = (wv >> 1) << 6;   // wave's 64-row offset
  const int wn   = (wv & 1) << 6;    // wave's 64-col offset
  const int ml   = lane & 31;        // A-row / B-col / D-col within 32-tile
  const int kh   = lane >> 5;        // k-half 0..1
  const int swzl = ml & 7;           // 3-bit row-derived chunk16 XOR

  f32x16_t acc[2][2];
#pragma unroll
  for (int i = 0; i < 2; ++i)
#pragma unroll
    for (int j = 0; j < 2; ++j)
#pragma unroll
      for (int r = 0; r < 16; ++r)
        acc[i][j][r] = 0.f;

  // Staging: LDS chunk16 (row, c) stores global chunk (row, c ^ (row&7)).
  const long ldA2 = (long)lda * 2, ldB2 = (long)ldb * 2;
  const int rowA = tid >> 3;
  const int csw  = (tid & 7) ^ (rowA & 7);
  const char* pA = (const char*)(Ab + (long)bm0 * lda) + (long)rowA * ldA2 + (csw << 4);
  const char* pB = (const char*)(Bb + (long)bn0 * ldb) + (long)rowA * ldB2 + (csw << 4);
  const int ldsbo = tid * 16;

  for (int k0 = 0; k0 < Keff; k0 += 64) {
    const long kb = (long)k0 * 2;
#pragma unroll
    for (int r = 0; r < 4; ++r)
      __builtin_amdgcn_global_load_lds(
          (const __attribute__((address_space(1))) unsigned int*)(pA + kb + (long)(r * 32) * ldA2),
          (__attribute__((address_space(3))) unsigned int*)((char*)lA + ldsbo + r * 4096), 16, 0, 0);
#pragma unroll
    for (int r = 0; r < 4; ++r)
      __builtin_amdgcn_global_load_lds(
          (const __attribute__((address_space(1))) unsigned int*)(pB + kb + (long)(r * 32) * ldB2),
          (__attribute__((address_space(3))) unsigned int*)((char*)lB + ldsbo + r * 4096), 16, 0, 0);
    __syncthreads();

    // logical k-chunk (s*2+kh) of row r lives at LDS chunk (s*2+kh)^(r&7)
#pragma unroll
    for (int s = 0; s < 4; ++s) {
      const int ck = ((s * 2 + kh) ^ swzl) << 3;   // u16 offset in 64-elem row
      bf16x8_t A0 = *(const bf16x8_t*)&lA[(wm + ml) * 64 + ck];
      bf16x8_t A1 = *(const bf16x8_t*)&lA[(wm + 32 + ml) * 64 + ck];
      bf16x8_t B0 = *(const bf16x8_t*)&lB[(wn + ml) * 64 + ck];
      bf16x8_t B1 = *(const bf16x8_t*)&lB[(wn + 32 + ml) * 64 + ck];
      acc[0][0] = __builtin_amdgcn_mfma_f32_32x32x16_bf16(A0, B0, acc[0][0], 0, 0, 0);
      acc[0][1] = __builtin_amdgcn_mfma_f32_32x32x16_bf16(A0, B1, acc[0][1], 0, 0, 0);
      acc[1][0] = __builtin_amdgcn_mfma_f32_32x32x16_bf16(A1, B0, acc[1][0], 0, 0, 0);
      acc[1][1] = __builtin_amdgcn_mfma_f32_32x32x16_bf16(A1, B1, acc[1][1], 0, 0, 0);
    }
    __syncthreads();
  }

  // epilogue: 32x32 D layout col=lane&31, row=(reg&3)+8*(reg>>2)+4*(lane>>5)
  if (OUTMODE == 3) {
    // E = exp(acc/32), causal mask on diagonal block, bf16 store, atomic rowsums.
    const float scale = 0.03125f;
    const bool diag = (bm0 == bn0);
    u16* Cb16 = (u16*)Cv + bz * sC;
    float* rsb = rs + bz * 2048;
#pragma unroll
    for (int i = 0; i < 2; ++i) {
#pragma unroll
      for (int reg = 0; reg < 16; ++reg) {
        const int grow = bm0 + wm + i * 32 + (reg & 3) + 8 * (reg >> 2) + kh * 4;
        const int col0 = bn0 + wn + ml;
        float e0 = (diag && col0 > grow)      ? 0.f : __expf(acc[i][0][reg] * scale);
        float e1 = (diag && col0 + 32 > grow) ? 0.f : __expf(acc[i][1][reg] * scale);
        Cb16[(long)grow * ldc + col0]      = f2bf(e0);
        Cb16[(long)grow * ldc + col0 + 32] = f2bf(e1);
        float rsum = e0 + e1;
#pragma unroll
        for (int m = 1; m < 32; m <<= 1) rsum += __shfl_xor(rsum, m);
        if (ml == 0) atomicAdd(&rsb[grow], rsum);
      }
    }
    return;
  }

  if (OUTMODE == 4) {
    // stage inverse rowsums through LDS (reuse lA; loop's final barrier protects)
    float* rsl = (float*)lA;
    if (tid < 128) rsl[tid] = 1.0f / rs[bz * 2048 + bm0 + tid];
    __syncthreads();
    u16* Cb16 = (u16*)Cv + bz * sC;
#pragma unroll
    for (int i = 0; i < 2; ++i)
#pragma unroll
      for (int j = 0; j < 2; ++j)
#pragma unroll
        for (int reg = 0; reg < 16; ++reg) {
          const int rl  = wm + i * 32 + (reg & 3) + 8 * (reg >> 2) + kh * 4;
          const int col = bn0 + wn + j * 32 + ml;
          Cb16[(long)(bm0 + rl) * ldc + col] = f2bf(acc[i][j][reg] * rsl[rl]);
        }
    return;
  }

  // OUTMODE 1: f32 + bias (proj)
  float* Cf32 = (float*)Cv + bz * sC;
#pragma unroll
  for (int i = 0; i < 2; ++i)
#pragma unroll
    for (int j = 0; j < 2; ++j)
#pragma unroll
      for (int reg = 0; reg < 16; ++reg) {
        const int row = bm0 + wm + i * 32 + (reg & 3) + 8 * (reg >> 2) + kh * 4;
        const int col = bn0 + wn + j * 32 + ml;
        Cf32[(long)row * ldc + col] = acc[i][j][reg] + bias[col];
      }
}

// ---------------------------------------------------------------------------
__global__ __launch_bounds__(256)
void cvt_f32_bf16(const float* __restrict__ in, u16* __restrict__ out) {
  const int i = blockIdx.x * 256 + threadIdx.x;
  float4 v = ((const float4*)in)[i];
  u16x4 o = {f2bf(v.x), f2bf(v.y), f2bf(v.z), f2bf(v.w)};
  ((u16x4*)out)[i] = o;
}

// both weight transposes in one dispatch
__global__ __launch_bounds__(256)
void transpose_weights(const float* __restrict__ wqkv, u16* __restrict__ wqkvT,
                       const float* __restrict__ wproj, u16* __restrict__ wprojT) {
  const bool isq = blockIdx.x < 96;
  const float* in = isq ? wqkv : wproj;
  u16* out        = isq ? wqkvT : wprojT;
  const int C     = isq ? 3072 : 1024;
  const int c0 = (isq ? blockIdx.x : (blockIdx.x - 96)) * 32;
  const int r0 = blockIdx.y * 32;
  __shared__ float t[32][33];
  const int tx = threadIdx.x & 31, ty = threadIdx.x >> 5;
#pragma unroll
  for (int i = 0; i < 32; i += 8)
    t[ty + i][tx] = in[(long)(r0 + ty + i) * C + (c0 + tx)];
  __syncthreads();
#pragma unroll
  for (int i = 0; i < 32; i += 8)
    out[(long)(c0 + ty + i) * 1024 + (r0 + tx)] = f2bf(t[tx][ty + i]);
}

// ---------------------------------------------------------------------------
extern "C" void kernel_launch(void* const* d_in, const int* in_sizes, int n_in,
                              void* d_out, int out_size, void* d_ws, size_t ws_size,
                              hipStream_t stream) {
  (void)in_sizes; (void)n_in; (void)out_size; (void)ws_size;
  const float* x      = (const float*)d_in[0];
  const float* w_qkv  = (const float*)d_in[1];
  const float* w_proj = (const float*)d_in[2];
  const float* b_proj = (const float*)d_in[3];
  float* y = (float*)d_out;
  char*  ws = (char*)d_ws;

  // workspace layout
  u16* xbf    = (u16*)(ws);                  // 16 MB  x bf16; reused for attn_out
  u16* qk     = (u16*)(ws + (16l << 20));    // 32 MB  [4][2048][2048] bf16 (q | k)
  u16* wqkvT  = (u16*)(ws + (48l << 20));    //  6 MB  [3072,1024]
  u16* wprojT = (u16*)(ws + (54l << 20));    //  2 MB  [1024,1024]
  u16* vT     = (u16*)(ws + (56l << 20));    // 16 MB  [4][1024][2048]
  u16* E      = (u16*)(ws + (72l << 20));    // 32 MB  [4][2048][2048] unnormalized exp
  float* rsum = (float*)(ws + (104l << 20)); // 32 KB  [4][2048] fp32 rowsums
  u16* attn   = xbf;                         // lifetime-disjoint reuse

  // 0) zero rowsums (ws is re-poisoned 0xAA before every launch)
  hipMemsetAsync(rsum, 0, 4 * 2048 * sizeof(float), stream);
  // 1) x -> bf16
  cvt_f32_bf16<<<8192, 256, 0, stream>>>(x, xbf);
  // 2) weights -> transposed bf16
  transpose_weights<<<dim3(128, 32), 256, 0, stream>>>(w_qkv, wqkvT, w_proj, wprojT);
  // 3) qkv = x @ w_qkv : q,k -> qk (ldc 2048), v -> vT fused transpose  [super-phase]
  gemm8p<2><<<dim3(12, 32), 512, 0, stream>>>(
      xbf, wqkvT, qk, vT, nullptr, 1024, 1024, 1024, 2048);
  // 4) E = exp(q @ k^T / 32) causal, + rowsums; compact triangular grid
  gemm_bt<3, 1><<<dim3(136, 1, 4), 256, 0, stream>>>(
      qk, qk + 1024, E, nullptr, nullptr, rsum, 1024, 2048, 2048, 2048,
      (long)2048 * 2048, (long)2048 * 2048, (long)2048 * 2048);
  // 5) attn = (E @ V) / rowsum : K_eff = bm0+128, longest blocks first
  gemm_bt<4, 2><<<dim3(8, 16, 4), 256, 0, stream>>>(
      E, vT, attn, nullptr, nullptr, rsum, 2048, 2048, 2048, 1024,
      (long)2048 * 2048, (long)1024 * 2048, (long)2048 * 1024);
  // 6) y = attn @ w_proj + b_proj : fp32 out  [legacy 128x128, 512 blocks]
  gemm_bt<1, 0><<<dim3(8, 64, 1), 256, 0, stream>>>(
      attn, wprojT, y, nullptr, b_proj, nullptr, 1024, 1024, 1024, 1024, 0, 0, 0);
}

// Round 3
// 274.269 us; speedup vs baseline: 1.0406x; 1.0239x over previous
//
#include <hip/hip_runtime.h>

// TinyAttention on MI355X: b=4, t=2048, d=1024, single head.
// R10: revert QKV to the proven legacy 128x128 kernel (R8/R9's 256^2 8-phase
// landed at 75-76us vs legacy 72us: LDS-fragment-traffic-bound at 1 block/CU
// with 1.5-round grid quantization; branch abandoned). Main change: remove the
// S-kernel rowsum atomics (139k device-scope atomicAdds on 8K hot floats,
// cross-XCD cacheline contention) — PV now computes rowsums itself from the
// E tiles it already stages in LDS (bank-staggered extra pass, 2 threads/row),
// and divides at the end. rsum buffer + memset + cross-dispatch dependency gone.

typedef __bf16 bf16x8_t __attribute__((ext_vector_type(8)));
typedef float  f32x16_t __attribute__((ext_vector_type(16)));
typedef unsigned short u16;

struct alignas(8) u16x4 { u16 x, y, z, w; };

__device__ inline float bf2f(u16 u) {
  union { unsigned u; float f; } c; c.u = ((unsigned)u) << 16; return c.f;
}
__device__ inline u16 f2bf(float f) {  // round-to-nearest-even
  union { float f; unsigned u; } c; c.f = f;
  unsigned r = c.u + 0x7fffu + ((c.u >> 16) & 1u);
  return (u16)(r >> 16);
}

// OUTMODE: 1 = f32 row-major + bias (proj), 2 = QKV split (qk row-major | vT col-major),
//          3 = S: E=exp(scale*acc) bf16 + causal mask (no rowsums — PV computes them)
//          4 = PV: bf16 row-major, divided by rowsum computed in-loop from E tiles
// GRIDMODE: 0 = normal, 1 = compact lower-triangular, 2 = reversed-y + K<=bm0+128
template<int OUTMODE, int GRIDMODE>
__global__ __launch_bounds__(256, 4)
void gemm_bt(const u16* __restrict__ A, const u16* __restrict__ B,
             void* __restrict__ Cv, u16* __restrict__ C2,
             const float* __restrict__ bias,
             int K, int lda, int ldb, int ldc,
             long sA, long sB, long sC)
{
  int bn0, bm0;
  if (GRIDMODE == 1) {
    const int x = blockIdx.x;                       // 0..135
    int r = (int)((sqrtf(8.f * x + 1.f) - 1.f) * 0.5f);
    while ((r + 1) * (r + 2) / 2 <= x) ++r;
    while (r * (r + 1) / 2 > x) --r;
    bm0 = r * 128;
    bn0 = (x - r * (r + 1) / 2) * 128;
  } else if (GRIDMODE == 2) {
    bn0 = blockIdx.x * 128;
    bm0 = ((int)gridDim.y - 1 - (int)blockIdx.y) * 128;  // longest K first
  } else {
    bn0 = blockIdx.x * 128;
    bm0 = blockIdx.y * 128;
  }
  const long bz = blockIdx.z;
  const u16* Ab = A + bz * sA;
  const u16* Bb = B + bz * sB;
  const int Keff = (GRIDMODE == 2) ? min(K, bm0 + 128) : K;

  // BK=64: 128 rows x 64 u16 = 16 KB per matrix, 32 KB total
  __shared__ __align__(16) u16 lA[128 * 64];
  __shared__ __align__(16) u16 lB[128 * 64];

  const int tid  = threadIdx.x;
  const int lane = tid & 63;
  const int wv   = tid >> 6;
  const int wm   = (wv >> 1) << 6;   // wave's 64-row offset
  const int wn   = (wv & 1) << 6;    // wave's 64-col offset
  const int ml   = lane & 31;        // A-row / B-col / D-col within 32-tile
  const int kh   = lane >> 5;        // k-half 0..1
  const int swz  = ml & 7;           // 3-bit row-derived chunk16 XOR

  f32x16_t acc[2][2];
#pragma unroll
  for (int i = 0; i < 2; ++i)
#pragma unroll
    for (int j = 0; j < 2; ++j)
#pragma unroll
      for (int r = 0; r < 16; ++r)
        acc[i][j][r] = 0.f;

  float rsacc = 0.f;   // OUTMODE 4: per-thread partial rowsum (row tid>>1, half tid&1)

  // Staging: LDS chunk16 (row, c) stores global chunk (row, c ^ (row&7)).
  const long ldA2 = (long)lda * 2, ldB2 = (long)ldb * 2;
  const int rowA = tid >> 3;
  const int csw  = (tid & 7) ^ (rowA & 7);
  const char* pA = (const char*)(Ab + (long)bm0 * lda) + (long)rowA * ldA2 + (csw << 4);
  const char* pB = (const char*)(Bb + (long)bn0 * ldb) + (long)rowA * ldB2 + (csw << 4);
  const int ldsbo = tid * 16;

  for (int k0 = 0; k0 < Keff; k0 += 64) {
    const long kb = (long)k0 * 2;
#pragma unroll
    for (int r = 0; r < 4; ++r)
      __builtin_amdgcn_global_load_lds(
          (const __attribute__((address_space(1))) unsigned int*)(pA + kb + (long)(r * 32) * ldA2),
          (__attribute__((address_space(3))) unsigned int*)((char*)lA + ldsbo + r * 4096), 16, 0, 0);
#pragma unroll
    for (int r = 0; r < 4; ++r)
      __builtin_amdgcn_global_load_lds(
          (const __attribute__((address_space(1))) unsigned int*)(pB + kb + (long)(r * 32) * ldB2),
          (__attribute__((address_space(3))) unsigned int*)((char*)lB + ldsbo + r * 4096), 16, 0, 0);
    __syncthreads();

    // logical k-chunk (s*2+kh) of row r lives at LDS chunk (s*2+kh)^(r&7)
#pragma unroll
    for (int s = 0; s < 4; ++s) {
      const int ck = ((s * 2 + kh) ^ swz) << 3;    // u16 offset in 64-elem row
      bf16x8_t a0 = *(const bf16x8_t*)&lA[(wm + ml) * 64 + ck];
      bf16x8_t a1 = *(const bf16x8_t*)&lA[(wm + 32 + ml) * 64 + ck];
      bf16x8_t b0 = *(const bf16x8_t*)&lB[(wn + ml) * 64 + ck];
      bf16x8_t b1 = *(const bf16x8_t*)&lB[(wn + 32 + ml) * 64 + ck];
      acc[0][0] = __builtin_amdgcn_mfma_f32_32x32x16_bf16(a0, b0, acc[0][0], 0, 0, 0);
      acc[0][1] = __builtin_amdgcn_mfma_f32_32x32x16_bf16(a0, b1, acc[0][1], 0, 0, 0);
      acc[1][0] = __builtin_amdgcn_mfma_f32_32x32x16_bf16(a1, b0, acc[1][0], 0, 0, 0);
      acc[1][1] = __builtin_amdgcn_mfma_f32_32x32x16_bf16(a1, b1, acc[1][1], 0, 0, 0);
    }

    if (OUTMODE == 4) {
      // Rowsum of the staged E tile (A operand): 2 threads per row, 4 chunks each.
      // Chunk order cc = h*4 + ((c+row)&3): each 16-lane phase hits 8 distinct
      // 16B bank-groups x2 (2-way = free). Sum is chunk-permutation-invariant,
      // so the XOR-swizzled physical layout doesn't matter.
      const int rr = tid >> 1;
      const int hh = (tid & 1) << 2;
#pragma unroll
      for (int c = 0; c < 4; ++c) {
        const int cc = hh + ((c + rr) & 3);
        bf16x8_t v = *(const bf16x8_t*)&lA[rr * 64 + cc * 8];
#pragma unroll
        for (int e = 0; e < 8; ++e) rsacc += (float)v[e];
      }
    }
    __syncthreads();
  }

  // epilogue: 32x32 D layout col=lane&31, row=(reg&3)+8*(reg>>2)+4*(lane>>5)
  if (OUTMODE == 2) {
    if (bn0 >= 2048) {
      // V columns: write vT[batch][dcol][s] col-major, u16x4 over 4 consecutive rows
#pragma unroll
      for (int i = 0; i < 2; ++i) {
#pragma unroll
        for (int g = 0; g < 4; ++g) {
          const int rowb = bm0 + wm + i * 32 + g * 8 + kh * 4;
          const int b_  = rowb >> 11;
          const int s_  = rowb & 2047;
#pragma unroll
          for (int j = 0; j < 2; ++j) {
            const int dcol = bn0 - 2048 + wn + j * 32 + ml;
            u16x4 o = {f2bf(acc[i][j][g * 4 + 0]), f2bf(acc[i][j][g * 4 + 1]),
                       f2bf(acc[i][j][g * 4 + 2]), f2bf(acc[i][j][g * 4 + 3])};
            *(u16x4*)&C2[(((long)b_ * 1024 + dcol) << 11) + s_] = o;
          }
        }
      }
    } else {
      u16* Cb16 = (u16*)Cv;
#pragma unroll
      for (int i = 0; i < 2; ++i)
#pragma unroll
        for (int j = 0; j < 2; ++j)
#pragma unroll
          for (int reg = 0; reg < 16; ++reg) {
            const int row = bm0 + wm + i * 32 + (reg & 3) + 8 * (reg >> 2) + kh * 4;
            const int col = bn0 + wn + j * 32 + ml;
            Cb16[(long)row * ldc + col] = f2bf(acc[i][j][reg]);
          }
    }
    return;
  }

  if (OUTMODE == 3) {
    // E = exp(acc/32), causal mask on diagonal block, bf16 store. No rowsums.
    const float scale = 0.03125f;
    const bool diag = (bm0 == bn0);
    u16* Cb16 = (u16*)Cv + bz * sC;
#pragma unroll
    for (int i = 0; i < 2; ++i) {
#pragma unroll
      for (int reg = 0; reg < 16; ++reg) {
        const int grow = bm0 + wm + i * 32 + (reg & 3) + 8 * (reg >> 2) + kh * 4;
        const int col0 = bn0 + wn + ml;
        float e0 = (diag && col0 > grow)      ? 0.f : __expf(acc[i][0][reg] * scale);
        float e1 = (diag && col0 + 32 > grow) ? 0.f : __expf(acc[i][1][reg] * scale);
        Cb16[(long)grow * ldc + col0]      = f2bf(e0);
        Cb16[(long)grow * ldc + col0 + 32] = f2bf(e1);
      }
    }
    return;
  }

  if (OUTMODE == 4) {
    // combine the 2 per-row partials via LDS, invert once per row
    float* rsl = (float*)lA;
    rsl[tid] = rsacc;
    __syncthreads();
    float* rinv = (float*)lB;
    if (tid < 128) rinv[tid] = 1.0f / (rsl[2 * tid] + rsl[2 * tid + 1]);
    __syncthreads();
    u16* Cb16 = (u16*)Cv + bz * sC;
#pragma unroll
    for (int i = 0; i < 2; ++i)
#pragma unroll
      for (int j = 0; j < 2; ++j)
#pragma unroll
        for (int reg = 0; reg < 16; ++reg) {
          const int rl  = wm + i * 32 + (reg & 3) + 8 * (reg >> 2) + kh * 4;
          const int col = bn0 + wn + j * 32 + ml;
          Cb16[(long)(bm0 + rl) * ldc + col] = f2bf(acc[i][j][reg] * rinv[rl]);
        }
    return;
  }

  // OUTMODE 1: f32 + bias (proj)
  float* Cf32 = (float*)Cv + bz * sC;
#pragma unroll
  for (int i = 0; i < 2; ++i)
#pragma unroll
    for (int j = 0; j < 2; ++j)
#pragma unroll
      for (int reg = 0; reg < 16; ++reg) {
        const int row = bm0 + wm + i * 32 + (reg & 3) + 8 * (reg >> 2) + kh * 4;
        const int col = bn0 + wn + j * 32 + ml;
        Cf32[(long)row * ldc + col] = acc[i][j][reg] + bias[col];
      }
}

// ---------------------------------------------------------------------------
__global__ __launch_bounds__(256)
void cvt_f32_bf16(const float* __restrict__ in, u16* __restrict__ out) {
  const int i = blockIdx.x * 256 + threadIdx.x;
  float4 v = ((const float4*)in)[i];
  u16x4 o = {f2bf(v.x), f2bf(v.y), f2bf(v.z), f2bf(v.w)};
  ((u16x4*)out)[i] = o;
}

// both weight transposes in one dispatch
__global__ __launch_bounds__(256)
void transpose_weights(const float* __restrict__ wqkv, u16* __restrict__ wqkvT,
                       const float* __restrict__ wproj, u16* __restrict__ wprojT) {
  const bool isq = blockIdx.x < 96;
  const float* in = isq ? wqkv : wproj;
  u16* out        = isq ? wqkvT : wprojT;
  const int C     = isq ? 3072 : 1024;
  const int c0 = (isq ? blockIdx.x : (blockIdx.x - 96)) * 32;
  const int r0 = blockIdx.y * 32;
  __shared__ float t[32][33];
  const int tx = threadIdx.x & 31, ty = threadIdx.x >> 5;
#pragma unroll
  for (int i = 0; i < 32; i += 8)
    t[ty + i][tx] = in[(long)(r0 + ty + i) * C + (c0 + tx)];
  __syncthreads();
#pragma unroll
  for (int i = 0; i < 32; i += 8)
    out[(long)(c0 + ty + i) * 1024 + (r0 + tx)] = f2bf(t[tx][ty + i]);
}

// ---------------------------------------------------------------------------
extern "C" void kernel_launch(void* const* d_in, const int* in_sizes, int n_in,
                              void* d_out, int out_size, void* d_ws, size_t ws_size,
                              hipStream_t stream) {
  (void)in_sizes; (void)n_in; (void)out_size; (void)ws_size;
  const float* x      = (const float*)d_in[0];
  const float* w_qkv  = (const float*)d_in[1];
  const float* w_proj = (const float*)d_in[2];
  const float* b_proj = (const float*)d_in[3];
  float* y = (float*)d_out;
  char*  ws = (char*)d_ws;

  // workspace layout
  u16* xbf    = (u16*)(ws);                  // 16 MB  x bf16; reused for attn_out
  u16* qk     = (u16*)(ws + (16l << 20));    // 32 MB  [4][2048][2048] bf16 (q | k)
  u16* wqkvT  = (u16*)(ws + (48l << 20));    //  6 MB  [3072,1024]
  u16* wprojT = (u16*)(ws + (54l << 20));    //  2 MB  [1024,1024]
  u16* vT     = (u16*)(ws + (56l << 20));    // 16 MB  [4][1024][2048]
  u16* E      = (u16*)(ws + (72l << 20));    // 32 MB  [4][2048][2048] unnormalized exp
  u16* attn   = xbf;                         // lifetime-disjoint reuse

  // 1) x -> bf16
  cvt_f32_bf16<<<8192, 256, 0, stream>>>(x, xbf);
  // 2) weights -> transposed bf16
  transpose_weights<<<dim3(128, 32), 256, 0, stream>>>(w_qkv, wqkvT, w_proj, wprojT);
  // 3) qkv = x @ w_qkv : q,k -> qk (ldc 2048), v -> vT fused transpose
  gemm_bt<2, 0><<<dim3(24, 64, 1), 256, 0, stream>>>(
      xbf, wqkvT, qk, vT, nullptr, 1024, 1024, 1024, 2048, 0, 0, 0);
  // 4) E = exp(q @ k^T / 32) causal; compact triangular grid (no rowsums)
  gemm_bt<3, 1><<<dim3(136, 1, 4), 256, 0, stream>>>(
      qk, qk + 1024, E, nullptr, nullptr, 1024, 2048, 2048, 2048,
      (long)2048 * 2048, (long)2048 * 2048, (long)2048 * 2048);
  // 5) attn = (E @ V) / rowsum(E) : rowsum computed in-loop from staged E tiles
  gemm_bt<4, 2><<<dim3(8, 16, 4), 256, 0, stream>>>(
      E, vT, attn, nullptr, nullptr, 2048, 2048, 2048, 1024,
      (long)2048 * 2048, (long)1024 * 2048, (long)2048 * 1024);
  // 6) y = attn @ w_proj + b_proj : fp32 out
  gemm_bt<1, 0><<<dim3(8, 64, 1), 256, 0, stream>>>(
      attn, wprojT, y, nullptr, b_proj, 1024, 1024, 1024, 1024, 0, 0, 0);
}

// Round 4
// 261.323 us; speedup vs baseline: 1.0921x; 1.0495x over previous
//
#include <hip/hip_runtime.h>

// TinyAttention on MI355X: b=4, t=2048, d=1024, single head.
// R11: swap the legacy 128x128 kernel's MFMA core from 32x32x16 to 16x16x32
// with R8's verified conflict-free LDS scheme: rows stored as [2 ksh][128][32k]
// (64B rows -> bank granule depends on row parity), chunk XOR ((row>>1)&3)
// pre-applied on the global_load_lds SOURCE and on the ds_read address.
// The 32x32 layout's 128B rows made granule = chunk (row drops out) -> a
// structural 4-way conflict (6.29M cycles/dispatch, ~14% of CU time) that no
// chunk-XOR could fix. Structure (grids, barriers, staging width, OUTMODEs,
// occupancy 4 blocks/CU) unchanged. Also: cvt + weight-transpose merged into
// one dispatch. R10's in-PV rowsum retained.

typedef __bf16 bf16x8_t __attribute__((ext_vector_type(8)));
typedef float  f32x4_t  __attribute__((ext_vector_type(4)));
typedef unsigned short u16;

struct alignas(8) u16x4 { u16 x, y, z, w; };

__device__ inline float bf2f(u16 u) {
  union { unsigned u; float f; } c; c.u = ((unsigned)u) << 16; return c.f;
}
__device__ inline u16 f2bf(float f) {  // round-to-nearest-even
  union { float f; unsigned u; } c; c.f = f;
  unsigned r = c.u + 0x7fffu + ((c.u >> 16) & 1u);
  return (u16)(r >> 16);
}

// OUTMODE: 1 = f32 row-major + bias (proj), 2 = QKV split (qk row-major | vT col-major),
//          3 = S: E=exp(scale*acc) bf16 + causal mask (no rowsums — PV computes them)
//          4 = PV: bf16 row-major, divided by rowsum computed in-loop from E tiles
// GRIDMODE: 0 = normal, 1 = compact lower-triangular, 2 = reversed-y + K<=bm0+128
template<int OUTMODE, int GRIDMODE>
__global__ __launch_bounds__(256, 4)
void gemm_bt(const u16* __restrict__ A, const u16* __restrict__ B,
             void* __restrict__ Cv, u16* __restrict__ C2,
             const float* __restrict__ bias,
             int K, int lda, int ldb, int ldc,
             long sA, long sB, long sC)
{
  int bn0, bm0;
  if (GRIDMODE == 1) {
    const int x = blockIdx.x;                       // 0..135
    int r = (int)((sqrtf(8.f * x + 1.f) - 1.f) * 0.5f);
    while ((r + 1) * (r + 2) / 2 <= x) ++r;
    while (r * (r + 1) / 2 > x) --r;
    bm0 = r * 128;
    bn0 = (x - r * (r + 1) / 2) * 128;
  } else if (GRIDMODE == 2) {
    bn0 = blockIdx.x * 128;
    bm0 = ((int)gridDim.y - 1 - (int)blockIdx.y) * 128;  // longest K first
  } else {
    bn0 = blockIdx.x * 128;
    bm0 = blockIdx.y * 128;
  }
  const long bz = blockIdx.z;
  const u16* Ab = A + bz * sA;
  const u16* Bb = B + bz * sB;
  const int Keff = (GRIDMODE == 2) ? min(K, bm0 + 128) : K;

  // BK=64 stored as [2 ksh][128 rows][32 k] per matrix: 16 KB each, 32 KB total.
  // 64B rows => bank granule (addr/16 mod 8) = (4*row + chunk) mod 8: the
  // ((row>>1)&3) chunk-XOR spreads 16-row fragment reads across all 8 groups.
  __shared__ __align__(16) u16 lA[2 * 128 * 32];
  __shared__ __align__(16) u16 lB[2 * 128 * 32];

  const int tid  = threadIdx.x;
  const int lane = tid & 63;
  const int wv   = tid >> 6;
  const int wm   = (wv >> 1) << 6;   // wave's 64-row offset
  const int wn   = (wv & 1) << 6;    // wave's 64-col offset
  const int l15  = lane & 15;
  // fragment read offset: row l15 (64B rows), chunk (lane>>4) ^ ((row>>1)&3)
  const int rd_off = l15 * 64 + ((((lane >> 4) ^ (l15 >> 1)) & 3) << 4);

  f32x4_t acc[4][4];
#pragma unroll
  for (int i = 0; i < 4; ++i)
#pragma unroll
    for (int j = 0; j < 4; ++j)
      acc[i][j] = (f32x4_t){0.f, 0.f, 0.f, 0.f};

  float rsacc = 0.f;   // OUTMODE 4: per-thread partial rowsum (row tid>>1, ksh tid&1)

  // Staging: thread t -> row t>>2, dest chunk t&3; source chunk pre-swizzled
  // c_src = (t&3) ^ ((row>>1)&3) = (t&3) ^ ((t>>3)&3).  4 shots per matrix:
  // shot r: rows += (r&1)*64, ksh = r>>1 (source +64B), dest += r*4096.
  const long ldA2 = (long)lda * 2, ldB2 = (long)ldb * 2;
  const int c_src = (tid & 3) ^ ((tid >> 3) & 3);
  const char* pA = (const char*)(Ab + (long)bm0 * lda) + (long)(tid >> 2) * ldA2 + (c_src << 4);
  const char* pB = (const char*)(Bb + (long)bn0 * ldb) + (long)(tid >> 2) * ldB2 + (c_src << 4);
  const int ldsbo = tid * 16;

  for (int k0 = 0; k0 < Keff; k0 += 64) {
    const long kb = (long)k0 * 2;
#pragma unroll
    for (int r = 0; r < 4; ++r) {
      const long go = (long)(r & 1) * 64 * ldA2 + (r >> 1) * 64;
      __builtin_amdgcn_global_load_lds(
          (const __attribute__((address_space(1))) unsigned int*)(pA + kb + go),
          (__attribute__((address_space(3))) unsigned int*)((char*)lA + ldsbo + r * 4096), 16, 0, 0);
    }
#pragma unroll
    for (int r = 0; r < 4; ++r) {
      const long go = (long)(r & 1) * 64 * ldB2 + (r >> 1) * 64;
      __builtin_amdgcn_global_load_lds(
          (const __attribute__((address_space(1))) unsigned int*)(pB + kb + go),
          (__attribute__((address_space(3))) unsigned int*)((char*)lB + ldsbo + r * 4096), 16, 0, 0);
    }
    __syncthreads();

    const char* lAb = (const char*)lA + wm * 64 + rd_off;
    const char* lBb = (const char*)lB + wn * 64 + rd_off;
#pragma unroll
    for (int s = 0; s < 2; ++s) {
      const int so = s * 8192;
      bf16x8_t b0 = *(const bf16x8_t*)(lBb + so + 0 * 1024);
      bf16x8_t b1 = *(const bf16x8_t*)(lBb + so + 1 * 1024);
      bf16x8_t b2 = *(const bf16x8_t*)(lBb + so + 2 * 1024);
      bf16x8_t b3 = *(const bf16x8_t*)(lBb + so + 3 * 1024);
#pragma unroll
      for (int mf = 0; mf < 4; ++mf) {
        bf16x8_t a = *(const bf16x8_t*)(lAb + so + mf * 1024);
        acc[mf][0] = __builtin_amdgcn_mfma_f32_16x16x32_bf16(a, b0, acc[mf][0], 0, 0, 0);
        acc[mf][1] = __builtin_amdgcn_mfma_f32_16x16x32_bf16(a, b1, acc[mf][1], 0, 0, 0);
        acc[mf][2] = __builtin_amdgcn_mfma_f32_16x16x32_bf16(a, b2, acc[mf][2], 0, 0, 0);
        acc[mf][3] = __builtin_amdgcn_mfma_f32_16x16x32_bf16(a, b3, acc[mf][3], 0, 0, 0);
      }
    }

    if (OUTMODE == 4) {
      // Rowsum of the staged E tile (A operand): 2 threads/row (ksh = tid&1),
      // 4 rotated chunks each. Sum is chunk-permutation-invariant, so the
      // swizzled physical layout doesn't matter.
      const int rr = tid >> 1;
      const int bsel = (tid & 1) * 8192;
#pragma unroll
      for (int c = 0; c < 4; ++c) {
        const int cc = (c + (rr >> 1)) & 3;
        bf16x8_t v = *(const bf16x8_t*)((const char*)lA + bsel + rr * 64 + cc * 16);
#pragma unroll
        for (int e = 0; e < 8; ++e) rsacc += (float)v[e];
      }
    }
    __syncthreads();
  }

  // epilogue: 16x16 D layout col=lane&15, row=(lane>>4)*4+reg
  const int r4 = (lane >> 4) << 2;

  if (OUTMODE == 2) {
    if (bn0 >= 2048) {
      // V columns: write vT[batch][dcol][s] col-major, u16x4 over 4 consecutive s
#pragma unroll
      for (int mf = 0; mf < 4; ++mf) {
        const int s0 = bm0 + wm + mf * 16 + r4;
        const int b_ = s0 >> 11;
        const int s_ = s0 & 2047;
#pragma unroll
        for (int nf = 0; nf < 4; ++nf) {
          const int dcol = bn0 - 2048 + wn + nf * 16 + l15;
          u16x4 o = {f2bf(acc[mf][nf][0]), f2bf(acc[mf][nf][1]),
                     f2bf(acc[mf][nf][2]), f2bf(acc[mf][nf][3])};
          *(u16x4*)&C2[(((long)b_ * 1024 + dcol) << 11) + s_] = o;
        }
      }
    } else {
      u16* Cb16 = (u16*)Cv;
#pragma unroll
      for (int mf = 0; mf < 4; ++mf)
#pragma unroll
        for (int nf = 0; nf < 4; ++nf) {
          const int col = bn0 + wn + nf * 16 + l15;
#pragma unroll
          for (int r = 0; r < 4; ++r)
            Cb16[(long)(bm0 + wm + mf * 16 + r4 + r) * ldc + col] = f2bf(acc[mf][nf][r]);
        }
    }
    return;
  }

  if (OUTMODE == 3) {
    // E = exp(acc/32), causal mask on diagonal block, bf16 store. No rowsums.
    const float scale = 0.03125f;
    const bool diag = (bm0 == bn0);
    u16* Cb16 = (u16*)Cv + bz * sC;
#pragma unroll
    for (int mf = 0; mf < 4; ++mf)
#pragma unroll
      for (int r = 0; r < 4; ++r) {
        const int grow = bm0 + wm + mf * 16 + r4 + r;
#pragma unroll
        for (int nf = 0; nf < 4; ++nf) {
          const int col = bn0 + wn + nf * 16 + l15;
          float e = (diag && col > grow) ? 0.f : __expf(acc[mf][nf][r] * scale);
          Cb16[(long)grow * ldc + col] = f2bf(e);
        }
      }
    return;
  }

  if (OUTMODE == 4) {
    // combine the 2 per-row partials via LDS, invert once per row
    float* rsl = (float*)lA;
    rsl[tid] = rsacc;
    __syncthreads();
    float* rinv = (float*)lB;
    if (tid < 128) rinv[tid] = 1.0f / (rsl[2 * tid] + rsl[2 * tid + 1]);
    __syncthreads();
    u16* Cb16 = (u16*)Cv + bz * sC;
#pragma unroll
    for (int mf = 0; mf < 4; ++mf)
#pragma unroll
      for (int nf = 0; nf < 4; ++nf) {
        const int col = bn0 + wn + nf * 16 + l15;
#pragma unroll
        for (int r = 0; r < 4; ++r) {
          const int rl = wm + mf * 16 + r4 + r;
          Cb16[(long)(bm0 + rl) * ldc + col] = f2bf(acc[mf][nf][r] * rinv[rl]);
        }
      }
    return;
  }

  // OUTMODE 1: f32 + bias (proj)
  float* Cf32 = (float*)Cv + bz * sC;
#pragma unroll
  for (int mf = 0; mf < 4; ++mf)
#pragma unroll
    for (int nf = 0; nf < 4; ++nf) {
      const int col = bn0 + wn + nf * 16 + l15;
      const float bb = bias[col];
#pragma unroll
      for (int r = 0; r < 4; ++r)
        Cf32[(long)(bm0 + wm + mf * 16 + r4 + r) * ldc + col] = acc[mf][nf][r] + bb;
    }
}

// ---------------------------------------------------------------------------
// merged: x -> bf16 (blocks 0..8191) + both weight transposes (blocks 8192..12287)
__global__ __launch_bounds__(256)
void prep(const float* __restrict__ x, u16* __restrict__ xbf,
          const float* __restrict__ wqkv, u16* __restrict__ wqkvT,
          const float* __restrict__ wproj, u16* __restrict__ wprojT) {
  const int bid = blockIdx.x;
  if (bid < 8192) {
    const int i = bid * 256 + threadIdx.x;
    float4 v = ((const float4*)x)[i];
    u16x4 o = {f2bf(v.x), f2bf(v.y), f2bf(v.z), f2bf(v.w)};
    ((u16x4*)xbf)[i] = o;
    return;
  }
  const int tb = bid - 8192;           // 0..4095
  const int bx = tb & 127;             // 0..127
  const int by = tb >> 7;              // 0..31
  const bool isq = bx < 96;
  const float* in = isq ? wqkv : wproj;
  u16* out        = isq ? wqkvT : wprojT;
  const int C     = isq ? 3072 : 1024;
  const int c0 = (isq ? bx : (bx - 96)) * 32;
  const int r0 = by * 32;
  __shared__ float t[32][33];
  const int tx = threadIdx.x & 31, ty = threadIdx.x >> 5;
#pragma unroll
  for (int i = 0; i < 32; i += 8)
    t[ty + i][tx] = in[(long)(r0 + ty + i) * C + (c0 + tx)];
  __syncthreads();
#pragma unroll
  for (int i = 0; i < 32; i += 8)
    out[(long)(c0 + ty + i) * 1024 + (r0 + tx)] = f2bf(t[tx][ty + i]);
}

// ---------------------------------------------------------------------------
extern "C" void kernel_launch(void* const* d_in, const int* in_sizes, int n_in,
                              void* d_out, int out_size, void* d_ws, size_t ws_size,
                              hipStream_t stream) {
  (void)in_sizes; (void)n_in; (void)out_size; (void)ws_size;
  const float* x      = (const float*)d_in[0];
  const float* w_qkv  = (const float*)d_in[1];
  const float* w_proj = (const float*)d_in[2];
  const float* b_proj = (const float*)d_in[3];
  float* y = (float*)d_out;
  char*  ws = (char*)d_ws;

  // workspace layout
  u16* xbf    = (u16*)(ws);                  // 16 MB  x bf16; reused for attn_out
  u16* qk     = (u16*)(ws + (16l << 20));    // 32 MB  [4][2048][2048] bf16 (q | k)
  u16* wqkvT  = (u16*)(ws + (48l << 20));    //  6 MB  [3072,1024]
  u16* wprojT = (u16*)(ws + (54l << 20));    //  2 MB  [1024,1024]
  u16* vT     = (u16*)(ws + (56l << 20));    // 16 MB  [4][1024][2048]
  u16* E      = (u16*)(ws + (72l << 20));    // 32 MB  [4][2048][2048] unnormalized exp
  u16* attn   = xbf;                         // lifetime-disjoint reuse

  // 1) x -> bf16, weights -> transposed bf16 (one dispatch)
  prep<<<12288, 256, 0, stream>>>(x, xbf, w_qkv, wqkvT, w_proj, wprojT);
  // 2) qkv = x @ w_qkv : q,k -> qk (ldc 2048), v -> vT fused transpose
  gemm_bt<2, 0><<<dim3(24, 64, 1), 256, 0, stream>>>(
      xbf, wqkvT, qk, vT, nullptr, 1024, 1024, 1024, 2048, 0, 0, 0);
  // 3) E = exp(q @ k^T / 32) causal; compact triangular grid (no rowsums)
  gemm_bt<3, 1><<<dim3(136, 1, 4), 256, 0, stream>>>(
      qk, qk + 1024, E, nullptr, nullptr, 1024, 2048, 2048, 2048,
      (long)2048 * 2048, (long)2048 * 2048, (long)2048 * 2048);
  // 4) attn = (E @ V) / rowsum(E) : rowsum computed in-loop from staged E tiles
  gemm_bt<4, 2><<<dim3(8, 16, 4), 256, 0, stream>>>(
      E, vT, attn, nullptr, nullptr, 2048, 2048, 2048, 1024,
      (long)2048 * 2048, (long)1024 * 2048, (long)2048 * 1024);
  // 5) y = attn @ w_proj + b_proj : fp32 out
  gemm_bt<1, 0><<<dim3(8, 64, 1), 256, 0, stream>>>(
      attn, wprojT, y, nullptr, b_proj, 1024, 1024, 1024, 1024, 0, 0, 0);
}